// Round 12
// baseline (265.100 us; speedup 1.0000x reference)
//
#include <hip/hip_runtime.h>

#define BATCH 16
#define NN 512   // n  (j index, "nxt" side; rows of X)
#define MM 512   // m  (i index, "cur" side; cols of X)
#define DD 128
#define QP_ITERS 20
#define NBLK (BATCH * 16)   // 256 blocks; 1/CU => all resident
#define SLOT 1024           // floats per block slot (512 x-partials + 512 qx)
#define QSTRIDE 524         // qtile LDS row stride
#define ALD 264             // A-stage LDS row stride in bf16 (528 B = 33*16)

typedef __attribute__((ext_vector_type(8))) short bf16x8;   // 8 bf16 = 4 VGPR
typedef __attribute__((ext_vector_type(4))) float f32x4;    // MFMA C/D

__device__ __forceinline__ unsigned short bf16_rne(float f) {
    unsigned u = __float_as_uint(f);
    return (unsigned short)((u + 0x7FFFu + ((u >> 16) & 1u)) >> 16);
}

__device__ __forceinline__ void split4(float4 v, uint2& hi, uint2& lo) {
    unsigned short h0 = bf16_rne(v.x), h1 = bf16_rne(v.y),
                   h2 = bf16_rne(v.z), h3 = bf16_rne(v.w);
    hi.x = (unsigned)h0 | ((unsigned)h1 << 16);
    hi.y = (unsigned)h2 | ((unsigned)h3 << 16);
    unsigned short l0 = bf16_rne(v.x - __uint_as_float((unsigned)h0 << 16));
    unsigned short l1 = bf16_rne(v.y - __uint_as_float((unsigned)h1 << 16));
    unsigned short l2 = bf16_rne(v.z - __uint_as_float((unsigned)h2 << 16));
    unsigned short l3 = bf16_rne(v.w - __uint_as_float((unsigned)h3 << 16));
    lo.x = (unsigned)l0 | ((unsigned)l1 << 16);
    lo.y = (unsigned)l2 | ((unsigned)l3 << 16);
}

union U8 { bf16x8 v; uint2 d[2]; uint4 q; };

__device__ __forceinline__ void split8(float4 v0, float4 v1,
                                       bf16x8& h8, bf16x8& l8) {
    uint2 h0, l0, h1, l1;
    split4(v0, h0, l0); split4(v1, h1, l1);
    U8 th, tl;
    th.d[0] = h0; th.d[1] = h1;
    tl.d[0] = l0; tl.d[1] = l1;
    h8 = th.v; l8 = tl.v;
}

__device__ __forceinline__ float dot4(float4 v) {
    return v.x*v.x + v.y*v.y + v.z*v.z + v.w*v.w;
}

// ---------------------------------------------------------------------------
// zero_flags: replaces hipMemsetAsync (measured ~60 us of stream overhead in
// this harness across R10/R11). Kernel->kernel ordering measured ~0 gap (R9).
// ---------------------------------------------------------------------------
__global__ void zero_flags_kernel(unsigned* __restrict__ flags)
{
    flags[threadIdx.x] = 0u;
}

// ---------------------------------------------------------------------------
__device__ __forceinline__ float gather16_sum_agent(const float* p)
{
    float acc = 0.f;
    #pragma unroll
    for (int g2 = 0; g2 < 16; ++g2)
        acc += __hip_atomic_load((float*)(p + g2 * SLOT), __ATOMIC_RELAXED,
                                 __HIP_MEMORY_SCOPE_AGENT);
    return acc;
}

// ---------------------------------------------------------------------------
// qp_fused v16 (R11-proven, 205 us dispatch, UNCHANGED): fused gemm+qp.
// A-tile staged in LDS as hi/lo bf16 (reg peak < 64 VGPR step: 52 VGPR,
// no spill); B reg-split; 3-pass MFMA; v14-proven iteration body with
// flags shifted +1 (sums round posts flag 1).
// ---------------------------------------------------------------------------
__global__ __launch_bounds__(1024, 4) void qp_fused_kernel(
    const float* __restrict__ nc, const float* __restrict__ ec,
    const float* __restrict__ nn, const float* __restrict__ en,
    float* __restrict__ part, float* __restrict__ sums_ex,
    unsigned* __restrict__ flags, float* __restrict__ out)
{
    __shared__ float lds[17424];             // 69.7 KB, phase-unioned
    __shared__ int sh_ok;
    float* stage = lds + 16384;              // qp iters: [1024] f | colq
    float* wred  = lds + 17408;              // [2] broadcast
    float* qtile = lds;                      // gemm out: [32][QSTRIDE]
    float* rcs   = lds + 32*QSTRIDE;         // [512] ||cur_i||^2 (both mats)
    float* rns   = lds + 32*QSTRIDE + 512;   // [32]  ||nxt_j||^2
    float* redz  = lds + 32*QSTRIDE + 544;   // [32]  qs/q2s wave partials
    unsigned short* sAh = (unsigned short*)lds;          // [32][ALD] hi
    unsigned short* sAl = (unsigned short*)lds + 32*ALD; // [32][ALD] lo
    // A-stage (33 KB) and qtile (67 KB) overlap: strictly sequential phases.

    int tid   = threadIdx.x;
    int blk   = blockIdx.x;
    int b     = blk >> 4;            // batch
    int g     = blk & 15;            // row-group: rows g*32..g*32+31
    int w     = tid >> 6;            // wave 0..15
    int lane  = tid & 63;
    int r_loc = tid >> 5;            // 0..31 local row
    int cseg  = tid & 31;            // owns cols cseg + 32k
    int j     = g * 32 + r_loc;
    size_t rowbase = ((size_t)b * NN + j) * MM;

    // ================= fused gemm phase =================
    // ---- stage A: 32 rows x 256 k (nn k0-127 | en k128-255), hi/lo ----
    {
        int r = tid >> 5, c = tid & 31;              // row, 8-float chunk
        const float* src = (c < 16 ? nn : en)
                         + ((size_t)b*NN + g*32 + r) * DD + (c & 15) * 8;
        float4 v0 = *(const float4*)(src);
        float4 v1 = *(const float4*)(src + 4);
        bf16x8 h8, l8;
        split8(v0, v1, h8, l8);
        U8 th, tl; th.v = h8; tl.v = l8;
        *(uint4*)&sAh[r*ALD + c*8] = th.q;
        *(uint4*)&sAl[r*ALD + c*8] = tl.q;
        float ns = dot4(v0) + dot4(v1);
        #pragma unroll
        for (int m = 1; m <= 16; m <<= 1) ns += __shfl_xor(ns, m);
        if (c == 0) rns[r] = ns;                     // full ||nn_j||^2+||en_j||^2
    }
    __syncthreads();                 // A staged

    {
        int lm = lane & 15, lg = lane >> 4;
        const float* bB[2] = { nc + (size_t)b*MM*DD,
                               ec + (size_t)b*MM*DD };

        f32x4 acc[2][2];             // [jf][if]
        #pragma unroll
        for (int a = 0; a < 2; ++a)
            #pragma unroll
            for (int c = 0; c < 2; ++c) acc[a][c] = (f32x4){0.f,0.f,0.f,0.f};
        float nb0 = 0.f, nb1 = 0.f;  // B-row norm partials

        #pragma unroll
        for (int s = 0; s < 8; ++s) {
            const int mt = s >> 2;                 // 0: node, 1: edge
            const int kb = (s & 3) * 32 + lg * 8;  // per-lane k in matrix
            const int ac = s * 32 + lg * 8;        // per-lane col in A stage
            // both B fragments first (resident: 16 VGPR)
            bf16x8 bh0, bl0, bh1, bl1;
            {
                const float* gb = bB[mt] + (size_t)(w*32 + lm)*DD + kb;
                float4 v0 = *(const float4*)(gb);
                float4 v1 = *(const float4*)(gb + 4);
                nb0 += dot4(v0) + dot4(v1);
                split8(v0, v1, bh0, bl0);
            }
            {
                const float* gb = bB[mt] + (size_t)(w*32 + 16 + lm)*DD + kb;
                float4 v0 = *(const float4*)(gb);
                float4 v1 = *(const float4*)(gb + 4);
                nb1 += dot4(v0) + dot4(v1);
                split8(v0, v1, bh1, bl1);
            }
            // per-jf: transient A frag from LDS (8 VGPR), 6 MFMA
            #pragma unroll
            for (int jf = 0; jf < 2; ++jf) {
                bf16x8 ah = *(const bf16x8*)&sAh[(jf*16 + lm)*ALD + ac];
                bf16x8 al = *(const bf16x8*)&sAl[(jf*16 + lm)*ALD + ac];
                acc[jf][0] = __builtin_amdgcn_mfma_f32_16x16x32_bf16(
                                 ah, bh0, acc[jf][0], 0, 0, 0);
                acc[jf][0] = __builtin_amdgcn_mfma_f32_16x16x32_bf16(
                                 ah, bl0, acc[jf][0], 0, 0, 0);
                acc[jf][0] = __builtin_amdgcn_mfma_f32_16x16x32_bf16(
                                 al, bh0, acc[jf][0], 0, 0, 0);
                acc[jf][1] = __builtin_amdgcn_mfma_f32_16x16x32_bf16(
                                 ah, bh1, acc[jf][1], 0, 0, 0);
                acc[jf][1] = __builtin_amdgcn_mfma_f32_16x16x32_bf16(
                                 ah, bl1, acc[jf][1], 0, 0, 0);
                acc[jf][1] = __builtin_amdgcn_mfma_f32_16x16x32_bf16(
                                 al, bh1, acc[jf][1], 0, 0, 0);
            }
        }

        // B norms: combine k-slices across lg variants (xor16, xor32)
        nb0 += __shfl_xor(nb0, 16); nb0 += __shfl_xor(nb0, 32);
        nb1 += __shfl_xor(nb1, 16); nb1 += __shfl_xor(nb1, 32);
        if (lane < 16) {
            rcs[w*32 + lane]      = nb0;
            rcs[w*32 + 16 + lane] = nb1;
        }
        __syncthreads();             // all A reads done; qtile may overwrite

        // scatter C-frags (v6/v15-proven C/D layout)
        #pragma unroll
        for (int jf = 0; jf < 2; ++jf)
            #pragma unroll
            for (int f = 0; f < 2; ++f)
                #pragma unroll
                for (int r = 0; r < 4; ++r)
                    qtile[(jf*16 + lg*4 + r)*QSTRIDE + w*32 + f*16 + lm]
                        = acc[jf][f][r];
    }
    __syncthreads();                 // qtile + rcs + rns visible

    // ---- extract q[16] + block sums ----
    float q[16];
    float qs = 0.f, q2s = 0.f;
    #pragma unroll
    for (int k = 0; k < 16; ++k) {
        float v = 0.5f*(rcs[cseg + 32*k] + rns[r_loc])
                - qtile[r_loc*QSTRIDE + cseg + 32*k];
        q[k] = v; qs += v; q2s += v*v;
    }
    #pragma unroll
    for (int m = 32; m; m >>= 1) {
        qs  += __shfl_xor(qs,  m);
        q2s += __shfl_xor(q2s, m);
    }
    if (lane == 0) { redz[w] = qs; redz[16 + w] = q2s; }
    __syncthreads();                 // redz visible (qtile now dead)

    unsigned* bflags = flags + b * 16;
    unsigned* myflag = bflags + g;
    if (tid == 0) {
        float s1 = 0.f, s2 = 0.f;
        #pragma unroll
        for (int i = 0; i < 16; ++i) { s1 += redz[i]; s2 += redz[16 + i]; }
        __hip_atomic_store(sums_ex + blk*2,     s1, __ATOMIC_RELAXED,
                           __HIP_MEMORY_SCOPE_AGENT);
        __hip_atomic_store(sums_ex + blk*2 + 1, s2, __ATOMIC_RELAXED,
                           __HIP_MEMORY_SCOPE_AGENT);
        __hip_atomic_store(myflag, 1u, __ATOMIC_RELEASE,
                           __HIP_MEMORY_SCOPE_AGENT);
    }

    // ---- sums exchange: lr, s1 (w0 poll + gather, one barrier) ----
    if (w == 0) {
        for (;;) {
            unsigned v = (lane < 16)
                ? __hip_atomic_load(bflags + lane, __ATOMIC_RELAXED,
                                    __HIP_MEMORY_SCOPE_AGENT)
                : 1u;
            if (__all(v >= 1u)) break;
        }
        float v1 = 0.f, v2 = 0.f;
        if (lane < 16) {
            const float* sp = sums_ex + (size_t)(b*16 + lane) * 2;
            v1 = __hip_atomic_load(sp,     __ATOMIC_RELAXED,
                                   __HIP_MEMORY_SCOPE_AGENT);
            v2 = __hip_atomic_load(sp + 1, __ATOMIC_RELAXED,
                                   __HIP_MEMORY_SCOPE_AGENT);
        }
        #pragma unroll
        for (int m = 32; m; m >>= 1) {
            v1 += __shfl_xor(v1, m);
            v2 += __shfl_xor(v2, m);
        }
        if (lane == 0) { wred[0] = v1; wred[1] = v2; }
    }
    __syncthreads();
    const float lr = 0.5f / (wred[1] + 1e-8f);
    const float inv_m = 1.0f / (float)MM;
    float s = wred[0] * inv_m;       // s1 = sum(qm)/m  (X0 = 1/m)

    float x[16], fk[16];
    #pragma unroll
    for (int k = 0; k < 16; ++k) { x[k] = inv_m; fk[k] = 1.0f; }

    // ================= v14-proven iteration body (flags shifted +1) ======
    for (int t = 1; t <= QP_ITERS; ++t) {
        if (t > 1) {
            unsigned tt = (unsigned)t;           // end-of-(t-1) posts t
            // ---- speculative probe (w0 only; relaxed) ----
            if (w == 0) {
                unsigned v = (lane < 16)
                    ? __hip_atomic_load(bflags + lane, __ATOMIC_RELAXED,
                                        __HIP_MEMORY_SCOPE_AGENT)
                    : tt;
                int ok = __all(v >= tt);
                if (lane == 0) sh_ok = ok;
            }
            __syncthreads();   // b1: broadcast sh_ok; prior lds reads done

            const float* p = part + (size_t)((t - 1) & 1) * (NBLK * SLOT)
                           + (size_t)b * (16 * SLOT) + tid;
            float acc = gather16_sum_agent(p);

            if (!sh_ok) {      // fallback: w0 relaxed poll + ordered re-gather
                if (w == 0) {
                    for (;;) {
                        unsigned v = (lane < 16)
                            ? __hip_atomic_load(bflags + lane, __ATOMIC_RELAXED,
                                                __HIP_MEMORY_SCOPE_AGENT)
                            : tt;
                        if (__all(v >= tt)) break;
                    }
                }
                __syncthreads();
                acc = gather16_sum_agent(p);
            }

            if (tid < 512) stage[tid] = fminf(1.0f, 2.0f / (acc + 1e-8f)); // f
            else           stage[tid] = acc;                               // colq
            __syncthreads();   // b2: stage visible

            // ---- per-wave redundant s-reduce ----
            float v = 0.f;
            #pragma unroll
            for (int kk = 0; kk < 8; ++kk) {
                int c = lane + 64 * kk;
                v += stage[c] * stage[512 + c];
            }
            #pragma unroll
            for (int m = 32; m; m >>= 1) v += __shfl_xor(v, m);
            s = v;
            #pragma unroll
            for (int k = 0; k < 16; ++k) fk[k] = stage[cseg + 32*k];
        }

        // ---- gradient step + clip + row normalize ----
        float c = 2.0f * lr * s;
        float rp = 0.f;
        #pragma unroll
        for (int k = 0; k < 16; ++k) {
            float v = x[k] * fk[k] - c * q[k];
            v = fminf(fmaxf(v, 0.f), 1.f);
            x[k] = v;
            rp += v;
        }
        #pragma unroll
        for (int m = 16; m; m >>= 1) rp += __shfl_xor(rp, m);
        float inv = 1.0f / (rp + 1e-8f);
        #pragma unroll
        for (int k = 0; k < 16; ++k) x[k] *= inv;

        // ---- column partial pass ----
        #pragma unroll
        for (int k = 0; k < 16; ++k) {
            float qx = q[k] * x[k];
            float px = x[k] + __shfl_xor(x[k], 32);   // row-pair sum
            float pq = qx   + __shfl_xor(qx,   32);
            int col = cseg + 32*k;
            if (lane < 32) lds[w * 512 + col]        = px;   // x partials
            else           lds[8192 + w * 512 + col] = pq;   // qx partials
        }
        __syncthreads();   // b4: col partials visible
        {
            int arr = tid >> 9;          // 0 => colsum(x), 1 => colsum(qx)
            int col = tid & 511;
            const float* basep = lds + arr * 8192 + col;
            float acc = 0.f;
            #pragma unroll
            for (int w2 = 0; w2 < 16; ++w2) acc += basep[w2 * 512];
            float* dst = part + (size_t)(t & 1) * (NBLK * SLOT)
                       + (size_t)blk * SLOT + tid;
            __hip_atomic_store(dst, acc, __ATOMIC_RELAXED,
                               __HIP_MEMORY_SCOPE_AGENT);
        }

        __syncthreads();   // b5: drain every thread's partial store
        if (tid == 0)
            __hip_atomic_store(myflag, (unsigned)(t + 1), __ATOMIC_RELEASE,
                               __HIP_MEMORY_SCOPE_AGENT);
    }

    // ---- final: poll (QP_ITERS+1) flags, gather colsum, scale, store ----
    {
        unsigned tt = (unsigned)(QP_ITERS + 1);
        if (w == 0) {
            for (;;) {
                unsigned v = (lane < 16)
                    ? __hip_atomic_load(bflags + lane, __ATOMIC_RELAXED,
                                        __HIP_MEMORY_SCOPE_AGENT)
                    : tt;
                if (__all(v >= tt)) break;
            }
        }
        __syncthreads();
        const float* p = part + (size_t)(QP_ITERS & 1) * (NBLK * SLOT)
                       + (size_t)b * (16 * SLOT) + tid;   // tid<512: x-partials
        if (tid < 512) {
            float acc = gather16_sum_agent(p);
            stage[tid] = fminf(1.0f, 2.0f / (acc + 1e-8f));
        }
        __syncthreads();
        #pragma unroll
        for (int k = 0; k < 16; ++k)
            out[rowbase + cseg + 32*k] = x[k] * stage[cseg + 32*k];
    }
}

// ---------------------------------------------------------------------------
extern "C" void kernel_launch(void* const* d_in, const int* in_sizes, int n_in,
                              void* d_out, int out_size, void* d_ws, size_t ws_size,
                              hipStream_t stream)
{
    const float* nc = (const float*)d_in[0];  // n_emb_cur (16,512,128)
    const float* ec = (const float*)d_in[1];  // e_emb_cur
    const float* nn = (const float*)d_in[2];  // n_emb_nxt
    const float* en = (const float*)d_in[3];  // e_emb_nxt
    float* out = (float*)d_out;               // (16, 512*512) fp32

    float* ws = (float*)d_ws;
    float* part    = ws;                                    // 2*NBLK*SLOT floats
    float* sums_ex = part + (size_t)2 * NBLK * SLOT;        // 512 floats
    unsigned* flags = (unsigned*)(sums_ex + 512);           // 256 words

    // flag reset via kernel (hipMemsetAsync measured ~60 us of stream
    // overhead in this harness; kernel->kernel gap measured ~0 in R9)
    zero_flags_kernel<<<dim3(1), dim3(NBLK), 0, stream>>>(flags);

    // 256 blocks x 16 waves, 70 KB LDS -> 1 block/CU, 256 <= 256 CUs:
    // all co-resident by construction.
    qp_fused_kernel<<<dim3(NBLK), dim3(1024), 0, stream>>>(
        nc, ec, nn, en, part, sums_ex, flags, out);
}

// Round 13
// 245.149 us; speedup vs baseline: 1.0814x; 1.0814x over previous
//
#include <hip/hip_runtime.h>

#define BATCH 16
#define NN 512   // n  (j index, "nxt" side; rows of X)
#define MM 512   // m  (i index, "cur" side; cols of X)
#define DD 128
#define QP_ITERS 20
#define NBLK (BATCH * 16)   // 256 qp blocks; 2-blocks/CU capacity => all resident
#define SLOT 1024           // floats per block slot (512 x-partials + 512 qx)

typedef __attribute__((ext_vector_type(8))) short bf16x8;   // 8 bf16 = 4 VGPR
typedef __attribute__((ext_vector_type(4))) float f32x4;    // MFMA C/D

#define LDR 56   // LDS row stride in bf16 units (112 B = 7*16: 16B-aligned rows)

__device__ __forceinline__ unsigned short bf16_rne(float f) {
    unsigned u = __float_as_uint(f);
    return (unsigned short)((u + 0x7FFFu + ((u >> 16) & 1u)) >> 16);
}

__device__ __forceinline__ void split4(float4 v, uint2& hi, uint2& lo) {
    unsigned short h0 = bf16_rne(v.x), h1 = bf16_rne(v.y),
                   h2 = bf16_rne(v.z), h3 = bf16_rne(v.w);
    hi.x = (unsigned)h0 | ((unsigned)h1 << 16);
    hi.y = (unsigned)h2 | ((unsigned)h3 << 16);
    unsigned short l0 = bf16_rne(v.x - __uint_as_float((unsigned)h0 << 16));
    unsigned short l1 = bf16_rne(v.y - __uint_as_float((unsigned)h1 << 16));
    unsigned short l2 = bf16_rne(v.z - __uint_as_float((unsigned)h2 << 16));
    unsigned short l3 = bf16_rne(v.w - __uint_as_float((unsigned)h3 << 16));
    lo.x = (unsigned)l0 | ((unsigned)l1 << 16);
    lo.y = (unsigned)l2 | ((unsigned)l3 << 16);
}

__device__ __forceinline__ float dot4(float4 v) {
    return v.x*v.x + v.y*v.y + v.z*v.z + v.w*v.w;
}

// ---------------------------------------------------------------------------
// gemm_q v6 (R9-proven best config, REVERTED verbatim): MFMA split-bf16
// with in-kernel conversion. ~30 us under the corrected overhead model.
// ---------------------------------------------------------------------------
__global__ __launch_bounds__(256, 2) void gemm_q_kernel(
    const float* __restrict__ nc, const float* __restrict__ ec,
    const float* __restrict__ nn, const float* __restrict__ en,
    float* __restrict__ qm, float* __restrict__ qsums,
    float* __restrict__ q2sums, unsigned* __restrict__ flags)
{
    int b  = blockIdx.z;
    int it = blockIdx.x;             // i tile, 128 wide (0..3)
    int jt = blockIdx.y;             // j tile,  64 wide (0..7)
    int tid = threadIdx.x;

    if (it == 0 && jt == 0 && b == 0) {          // zero qp flags (512 words)
        flags[tid] = 0u; flags[tid + 256] = 0u;
    }

    __shared__ __align__(16) unsigned short sAh[64 * LDR];    // 7 KB
    __shared__ __align__(16) unsigned short sAl[64 * LDR];    // 7 KB
    __shared__ __align__(16) unsigned short sBh[128 * LDR];   // 14 KB
    __shared__ __align__(16) unsigned short sBl[128 * LDR];   // 14 KB

    int l  = tid & 63;
    int wv = tid >> 6;               // wave 0..3
    int wi = wv & 1;                 // i-half:   ibase = wi*64
    int wj = wv >> 1;                // j-half:   jbase = wj*32
    int lm = l & 15;                 // frag row/col index
    int lg = l >> 4;                 // frag k-group

    // staging coords: A 64 rows x 32k (8 fp32/thread), B 128 x 32 (16/thread)
    int ar  = tid >> 2, akq = (tid & 3) * 8;     // A row, k-offset {0,8,16,24}
    int br  = tid >> 1, bk0 = (tid & 1) * 16;    // B row, k-offset {0,16}

    const float* aBase[2] = { nn + ((size_t)b*NN + jt*64)  * DD,
                              en + ((size_t)b*NN + jt*64)  * DD };
    const float* bBase[2] = { nc + ((size_t)b*MM + it*128) * DD,
                              ec + ((size_t)b*MM + it*128) * DD };

    f32x4 acc[2][4];                 // [jf][if]
    #pragma unroll
    for (int a = 0; a < 2; ++a)
        #pragma unroll
        for (int c = 0; c < 4; ++c) acc[a][c] = (f32x4){0.f, 0.f, 0.f, 0.f};

    float s_a = 0.f, s_b = 0.f;      // fp32 row-norm partials

    for (int s = 0; s < 8; ++s) {
        const float* ga = aBase[s >> 2] + (size_t)ar * DD + (s & 3) * 32 + akq;
        const float* gb = bBase[s >> 2] + (size_t)br * DD + (s & 3) * 32 + bk0;
        float4 va0 = *(const float4*)(ga);
        float4 va1 = *(const float4*)(ga + 4);
        float4 vb0 = *(const float4*)(gb);
        float4 vb1 = *(const float4*)(gb + 4);
        float4 vb2 = *(const float4*)(gb + 8);
        float4 vb3 = *(const float4*)(gb + 12);
        s_a += dot4(va0) + dot4(va1);
        s_b += dot4(vb0) + dot4(vb1) + dot4(vb2) + dot4(vb3);

        __syncthreads();             // previous step's frag reads complete
        {
            uint2 h, lo;
            split4(va0, h, lo);
            *(uint2*)&sAh[ar*LDR + akq]     = h; *(uint2*)&sAl[ar*LDR + akq]     = lo;
            split4(va1, h, lo);
            *(uint2*)&sAh[ar*LDR + akq + 4] = h; *(uint2*)&sAl[ar*LDR + akq + 4] = lo;
            split4(vb0, h, lo);
            *(uint2*)&sBh[br*LDR + bk0]      = h; *(uint2*)&sBl[br*LDR + bk0]      = lo;
            split4(vb1, h, lo);
            *(uint2*)&sBh[br*LDR + bk0 + 4]  = h; *(uint2*)&sBl[br*LDR + bk0 + 4]  = lo;
            split4(vb2, h, lo);
            *(uint2*)&sBh[br*LDR + bk0 + 8]  = h; *(uint2*)&sBl[br*LDR + bk0 + 8]  = lo;
            split4(vb3, h, lo);
            *(uint2*)&sBh[br*LDR + bk0 + 12] = h; *(uint2*)&sBl[br*LDR + bk0 + 12] = lo;
        }
        __syncthreads();             // staged tile visible

        bf16x8 ah[2], al[2];
        #pragma unroll
        for (int jf = 0; jf < 2; ++jf) {
            int rr = wj*32 + jf*16 + lm;
            ah[jf] = *(const bf16x8*)&sAh[rr*LDR + lg*8];
            al[jf] = *(const bf16x8*)&sAl[rr*LDR + lg*8];
        }
        #pragma unroll
        for (int ff = 0; ff < 4; ++ff) {
            int rr = wi*64 + ff*16 + lm;
            bf16x8 bh = *(const bf16x8*)&sBh[rr*LDR + lg*8];
            bf16x8 bl = *(const bf16x8*)&sBl[rr*LDR + lg*8];
            #pragma unroll
            for (int jf = 0; jf < 2; ++jf) {
                acc[jf][ff] = __builtin_amdgcn_mfma_f32_16x16x32_bf16(
                                  ah[jf], bh, acc[jf][ff], 0, 0, 0);
                acc[jf][ff] = __builtin_amdgcn_mfma_f32_16x16x32_bf16(
                                  ah[jf], bl, acc[jf][ff], 0, 0, 0);
                acc[jf][ff] = __builtin_amdgcn_mfma_f32_16x16x32_bf16(
                                  al[jf], bh, acc[jf][ff], 0, 0, 0);
            }
        }
    }

    // ---- row-norm combine through reused LDS ----
    __syncthreads();                 // k-loop LDS reads complete
    float* nA = (float*)sAh;         // 256 floats: partials for A row j at 4j..4j+3
    float* nB = nA + 256;            // 256 floats: partials for B row i at 2i..2i+1
    nA[tid] = s_a;                   // tid == 4*ar + (tid&3)
    nB[tid] = s_b;                   // tid == 2*br + (tid&1)
    __syncthreads();

    float rci[4];
    #pragma unroll
    for (int ff = 0; ff < 4; ++ff) {
        int i_loc = wi*64 + ff*16 + lm;
        rci[ff] = nB[2*i_loc] + nB[2*i_loc + 1];   // ||nc_i||^2 + ||ec_i||^2
    }

    float qs = 0.f, q2s = 0.f;
    #pragma unroll
    for (int jf = 0; jf < 2; ++jf) {
        #pragma unroll
        for (int r = 0; r < 4; ++r) {
            int j_loc = wj*32 + jf*16 + lg*4 + r;   // C/D row = (lane>>4)*4+reg
            float rnj = nA[4*j_loc] + nA[4*j_loc+1]
                      + nA[4*j_loc+2] + nA[4*j_loc+3];
            size_t rowp = ((size_t)b*NN + jt*64 + j_loc) * MM + it*128;
            #pragma unroll
            for (int ff = 0; ff < 4; ++ff) {
                float v = 0.5f * (rci[ff] + rnj) - acc[jf][ff][r];
                qm[rowp + wi*64 + ff*16 + lm] = v;
                qs += v; q2s += v * v;
            }
        }
    }

    #pragma unroll
    for (int off = 32; off; off >>= 1) {
        qs  += __shfl_down(qs,  off);
        q2s += __shfl_down(q2s, off);
    }
    __shared__ float red[8];
    int lane = tid & 63;
    if (lane == 0) { red[wv] = qs; red[4 + wv] = q2s; }
    __syncthreads();
    if (tid == 0) {
        int tile = b * 32 + jt * 4 + it;
        qsums[tile]  = red[0] + red[1] + red[2] + red[3];
        q2sums[tile] = red[4] + red[5] + red[6] + red[7];
    }
}

// ---------------------------------------------------------------------------
__device__ __forceinline__ float gather16_sum_agent(const float* p)
{
    float acc = 0.f;
    #pragma unroll
    for (int g2 = 0; g2 < 16; ++g2)
        acc += __hip_atomic_load((float*)(p + g2 * SLOT), __ATOMIC_RELAXED,
                                 __HIP_MEMORY_SCOPE_AGENT);
    return acc;
}

// ---------------------------------------------------------------------------
// qp_iter_kernel v14 (R9-proven best config, REVERTED verbatim): relaxed
// w0-only speculative probe + poll fallback; per-wave redundant s-reduce
// (b3 removed); 4 barriers/round.
// ---------------------------------------------------------------------------
__global__ __launch_bounds__(1024, 4) void qp_iter_kernel(
    const float* __restrict__ qm, const float* __restrict__ qsums,
    const float* __restrict__ q2sums, float* __restrict__ part,
    unsigned* __restrict__ flags, float* __restrict__ out)
{
    __shared__ float lds[16384 + 1024 + 16];  // col partials | stage | wred
    __shared__ int sh_ok;
    float* stage = lds + 16384;              // [1024]: 0..511 f, 512..1023 colq
    float* wred  = lds + 16384 + 1024;       // [2] prologue broadcast only

    int tid   = threadIdx.x;
    int blk   = blockIdx.x;
    int b     = blk >> 4;            // batch
    int g     = blk & 15;            // row-group: rows g*32..g*32+31
    int w     = tid >> 6;            // wave 0..15
    int lane  = tid & 63;
    int r_loc = tid >> 5;            // 0..31 local row
    int cseg  = tid & 31;            // owns cols cseg + 32k
    int j     = g * 32 + r_loc;

    size_t rowbase = ((size_t)b * NN + j) * MM;

    // ---- prologue: reduce 32 per-tile sums -> lr, s1 ----
    if (w == 0) {
        float v1 = (lane < 32) ? qsums[b * 32 + lane]  : 0.f;
        float v2 = (lane < 32) ? q2sums[b * 32 + lane] : 0.f;
        #pragma unroll
        for (int m = 32; m; m >>= 1) {
            v1 += __shfl_xor(v1, m);
            v2 += __shfl_xor(v2, m);
        }
        if (lane == 0) { wred[0] = v1; wred[1] = v2; }
    }

    float q[16], x[16], fk[16];
    #pragma unroll
    for (int k = 0; k < 16; ++k) q[k] = qm[rowbase + cseg + 32*k];

    const float inv_m = 1.0f / (float)MM;
    #pragma unroll
    for (int k = 0; k < 16; ++k) { x[k] = inv_m; fk[k] = 1.0f; }

    __syncthreads();
    const float lr = 0.5f / (wred[1] + 1e-8f);
    float s = wred[0] * inv_m;       // s1 = sum(qm)/m  (X0 = 1/m)

    unsigned* myflag = flags + b * 32 + g;
    unsigned* bflags = flags + b * 32;

    for (int t = 1; t <= QP_ITERS; ++t) {
        if (t > 1) {
            unsigned tt = (unsigned)(t - 1);
            // ---- speculative probe (w0 only; relaxed) ----
            if (w == 0) {
                unsigned v = (lane < 16)
                    ? __hip_atomic_load(bflags + lane, __ATOMIC_RELAXED,
                                        __HIP_MEMORY_SCOPE_AGENT)
                    : tt;
                int ok = __all(v >= tt);
                if (lane == 0) sh_ok = ok;
            }
            __syncthreads();   // b1: broadcast sh_ok; prior lds reads done

            const float* p = part + (size_t)((t - 1) & 1) * (NBLK * SLOT)
                           + (size_t)b * (16 * SLOT) + tid;
            float acc = gather16_sum_agent(p);

            if (!sh_ok) {      // fallback: w0 relaxed poll + ordered re-gather
                if (w == 0) {
                    for (;;) {
                        unsigned v = (lane < 16)
                            ? __hip_atomic_load(bflags + lane, __ATOMIC_RELAXED,
                                                __HIP_MEMORY_SCOPE_AGENT)
                            : tt;
                        if (__all(v >= tt)) break;
                    }
                }
                __syncthreads();
                acc = gather16_sum_agent(p);
            }

            if (tid < 512) stage[tid] = fminf(1.0f, 2.0f / (acc + 1e-8f)); // f
            else           stage[tid] = acc;                               // colq
            __syncthreads();   // b2: stage visible

            // ---- per-wave redundant s-reduce (b3 removed) ----
            float v = 0.f;
            #pragma unroll
            for (int kk = 0; kk < 8; ++kk) {
                int c = lane + 64 * kk;
                v += stage[c] * stage[512 + c];
            }
            #pragma unroll
            for (int m = 32; m; m >>= 1) v += __shfl_xor(v, m);
            s = v;
            #pragma unroll
            for (int k = 0; k < 16; ++k) fk[k] = stage[cseg + 32*k];
        }

        // ---- gradient step + clip + row normalize ----
        float c = 2.0f * lr * s;
        float rp = 0.f;
        #pragma unroll
        for (int k = 0; k < 16; ++k) {
            float v = x[k] * fk[k] - c * q[k];
            v = fminf(fmaxf(v, 0.f), 1.f);
            x[k] = v;
            rp += v;
        }
        #pragma unroll
        for (int m = 16; m; m >>= 1) rp += __shfl_xor(rp, m);
        float inv = 1.0f / (rp + 1e-8f);
        #pragma unroll
        for (int k = 0; k < 16; ++k) x[k] *= inv;

        // ---- column partial pass ----
        #pragma unroll
        for (int k = 0; k < 16; ++k) {
            float qx = q[k] * x[k];
            float px = x[k] + __shfl_xor(x[k], 32);   // row-pair sum
            float pq = qx   + __shfl_xor(qx,   32);
            int col = cseg + 32*k;
            if (lane < 32) lds[w * 512 + col]        = px;   // x partials
            else           lds[8192 + w * 512 + col] = pq;   // qx partials
        }
        __syncthreads();   // b4: col partials visible
        {
            int arr = tid >> 9;          // 0 => colsum(x), 1 => colsum(qx)
            int col = tid & 511;
            const float* basep = lds + arr * 8192 + col;
            float acc = 0.f;
            #pragma unroll
            for (int w2 = 0; w2 < 16; ++w2) acc += basep[w2 * 512];
            float* dst = part + (size_t)(t & 1) * (NBLK * SLOT)
                       + (size_t)blk * SLOT + tid;
            __hip_atomic_store(dst, acc, __ATOMIC_RELAXED,
                               __HIP_MEMORY_SCOPE_AGENT);
        }

        __syncthreads();   // b5: drain every thread's partial store
        if (tid == 0)
            __hip_atomic_store(myflag, (unsigned)t, __ATOMIC_RELEASE,
                               __HIP_MEMORY_SCOPE_AGENT);
    }

    // ---- final: poll iteration 20's flags, gather colsum, scale, store ----
    {
        unsigned tt = (unsigned)QP_ITERS;
        if (w == 0) {
            for (;;) {
                unsigned v = (lane < 16)
                    ? __hip_atomic_load(bflags + lane, __ATOMIC_RELAXED,
                                        __HIP_MEMORY_SCOPE_AGENT)
                    : tt;
                if (__all(v >= tt)) break;
            }
        }
        __syncthreads();
        const float* p = part + (size_t)(QP_ITERS & 1) * (NBLK * SLOT)
                       + (size_t)b * (16 * SLOT) + tid;   // tid<512: x-partials
        if (tid < 512) {
            float acc = gather16_sum_agent(p);
            stage[tid] = fminf(1.0f, 2.0f / (acc + 1e-8f));
        }
        __syncthreads();
        #pragma unroll
        for (int k = 0; k < 16; ++k)
            out[rowbase + cseg + 32*k] = x[k] * stage[cseg + 32*k];
    }
}

// ---------------------------------------------------------------------------
extern "C" void kernel_launch(void* const* d_in, const int* in_sizes, int n_in,
                              void* d_out, int out_size, void* d_ws, size_t ws_size,
                              hipStream_t stream)
{
    const float* nc = (const float*)d_in[0];  // n_emb_cur (16,512,128)
    const float* ec = (const float*)d_in[1];  // e_emb_cur
    const float* nn = (const float*)d_in[2];  // n_emb_nxt
    const float* en = (const float*)d_in[3];  // e_emb_nxt
    float* out = (float*)d_out;               // (16, 512*512) fp32

    float* ws = (float*)d_ws;
    const size_t QM_FLOATS = (size_t)BATCH * NN * MM;       // 4,194,304 (16 MB)

    float* qm   = ws;
    float* part = ws + QM_FLOATS;                           // 2*NBLK*SLOT floats
    float* qsums  = part + (size_t)2 * NBLK * SLOT;         // 512
    float* q2sums = qsums + 512;                            // 512
    unsigned* flags = (unsigned*)(q2sums + 512);            // 512 words

    gemm_q_kernel<<<dim3(4, 8, BATCH), 256, 0, stream>>>(nc, ec, nn, en, qm,
                                                         qsums, q2sums, flags);

    // NORMAL launch: capacity (2 blocks/CU x 256 CUs) >= 256 blocks ensures
    // co-residency; all inter-block sync is hand-rolled flag spins.
    qp_iter_kernel<<<dim3(NBLK), dim3(1024), 0, stream>>>(
        qm, qsums, q2sums, part, flags, out);
}